// Round 19
// baseline (58.143 us; speedup 1.0000x reference)
//
#include <hip/hip_runtime.h>
#include <math.h>

#define BB 8
#define CC 64
#define OO 64
#define HH 128
#define WW 128
#define PP 9
#define HWIMG 16384           // H*W per batch
#define NTOT  131072          // B*H*W
#define RSTR 144              // padded halo record stride (16B pad, no swizzle)

typedef __attribute__((ext_vector_type(8))) _Float16 h8;
typedef __attribute__((ext_vector_type(2))) _Float16 h2;
typedef __attribute__((ext_vector_type(4))) float f32x4;

// ---------------------------------------------------------------------------
// Kernel 0: prep (verbatim).
// ---------------------------------------------------------------------------
__global__ void k_prep(const float* __restrict__ w,
                       const float* __restrict__ dw_w,
                       const float* __restrict__ dw_b,
                       const float* __restrict__ gamma,
                       const float* __restrict__ beta,
                       const float* __restrict__ mean,
                       const float* __restrict__ var,
                       const float* __restrict__ pw_w,
                       const float* __restrict__ pw_b,
                       _Float16* __restrict__ wtf2,
                       float* __restrict__ dwt,
                       float* __restrict__ bnA,
                       float* __restrict__ bnB,
                       _Float16* __restrict__ pwa,
                       float* __restrict__ pwb) {
  int bid = blockIdx.x, t = threadIdx.x;
  if (bid < 144) {
    int i = bid * 256 + t;
    int e  = i & 7;
    int ln = (i >> 3) & 63;
    int kc = (i >> 9) & 1;
    int mt = (i >> 10) & 3;
    int p  = i >> 12;
    int o = mt * 16 + (ln & 15);
    int c = kc * 32 + (ln >> 4) * 8 + e;
    wtf2[i] = (_Float16)w[(o * 64 + c) * 9 + p];
  } else {
    if (t < 64) {
      float A = gamma[t] * rsqrtf(var[t] + 1e-5f);
      bnA[t] = A;
      bnB[t] = (dw_b[t] - mean[t]) * A + beta[t];
    }
    if (t < 32) pwb[t] = (t < 18) ? pw_b[t] : 0.f;
    for (int i = t; i < 576; i += 256) {
      int tap = i % 9, c = i / 9;
      dwt[tap * 64 + c] = dw_w[c * 9 + tap];
    }
    for (int i = t; i < 2048; i += 256) {
      int e  = i & 7;
      int ln = (i >> 3) & 63;
      int kc = (i >> 9) & 1;
      int mt = (i >> 10) & 1;
      int ko = mt * 16 + (ln & 15);
      int c  = kc * 32 + ((ln >> 4) & 3) * 8 + e;
      pwa[i] = (ko < 18) ? (_Float16)pw_w[ko * 64 + c] : (_Float16)0.f;
    }
  }
}

// ---------------------------------------------------------------------------
// Kernel 1: x NCHW f32 -> xt[b][pix][c] f16 (NHWC) (verbatim, known good)
// ---------------------------------------------------------------------------
__global__ void __launch_bounds__(256, 4)
k_tr(const float* __restrict__ x, _Float16* __restrict__ xt) {
  __shared__ _Float16 lt[64][66];
  int bid = blockIdx.x;
  int vbid = (bid & 7) * 256 + (bid >> 3);    // XCD k <- batch k
  int tid = threadIdx.x;
  int wid = tid >> 6, ln = tid & 63;
  int b = vbid >> 8;
  int pix0 = (vbid & 255) * 64;
  const float* xbb = x + (size_t)b * CC * HWIMG;

  #pragma unroll
  for (int i = 0; i < 8; ++i) {
    int c0 = (wid * 8 + i) * 2;
    float v0 = xbb[(size_t)c0 * HWIMG + pix0 + ln];
    float v1 = xbb[(size_t)(c0 + 1) * HWIMG + pix0 + ln];
    h2 hv;
    hv[0] = (_Float16)v0;
    hv[1] = (_Float16)v1;
    *(h2*)&lt[ln][c0] = hv;
  }
  __syncthreads();

  int pq = tid >> 2, q = tid & 3;
  h8 o0, o1;
  #pragma unroll
  for (int j = 0; j < 4; ++j) {
    h2 v = *(h2*)&lt[pq][q * 16 + 2 * j];
    o0[2 * j] = v[0];
    o0[2 * j + 1] = v[1];
  }
  #pragma unroll
  for (int j = 0; j < 4; ++j) {
    h2 v = *(h2*)&lt[pq][q * 16 + 8 + 2 * j];
    o1[2 * j] = v[0];
    o1[2 * j + 1] = v[1];
  }
  _Float16* op = xt + ((size_t)((b << 14) + pix0 + pq)) * 64 + q * 16;
  *(h8*)op = o0;
  *(h8*)(op + 8) = o1;
}

// ---------------------------------------------------------------------------
// Fused tile body — 4x16 px tile, 8x20 halo (23 KB), 1 pixel/thread.
// Wave w owns row ty0+w; lane (lk,lm): pixel col lm, k-slice lk.
// ---------------------------------------------------------------------------
template<bool BORDER>
__device__ __forceinline__ void tile_body(
    const _Float16* __restrict__ xb,
    const float* __restrict__ dwt,
    const float* __restrict__ bnA,
    const float* __restrict__ bnB,
    const _Float16* __restrict__ pwa,
    const float* __restrict__ pwb,
    const _Float16* __restrict__ wtf2,
    const float* __restrict__ bias,
    float* __restrict__ out,
    char* smem, int b, int ty0, int tx0, int tid) {
  int wid = tid >> 6, ln = tid & 63;
  int lm = ln & 15, lk = ln >> 4;

  // ---- stage 8x20 halo records (row/col-clamped), chunk j -> slot j
  for (int ch = tid; ch < 1280; ch += 256) {
    int rec = ch >> 3, j = ch & 7;
    int ry = rec / 20, rx = rec - ry * 20;
    int yy = min(max(ty0 - 2 + ry, 0), HH - 1);
    int xx = min(max(tx0 - 2 + rx, 0), WW - 1);
    h8 v = *((const h8*)(xb + ((size_t)((yy << 7) + xx)) * 64) + j);
    *(h8*)(smem + rec * RSTR + j * 16) = v;
  }
  __syncthreads();

  int row = ty0 + wid;            // this wave's pixel row

  // ======== Phase 1: offsets via MFMA (1 px/lane) ========
  float s[16];
  #pragma unroll
  for (int e = 0; e < 16; ++e) s[e] = 0.f;

  #pragma unroll
  for (int tap = 0; tap < 9; ++tap) {
    int dy = tap / 3 - 1, dx = tap % 3 - 1;
    const float* dwp = dwt + tap * 64;
    f32x4 d0a = *(const f32x4*)(dwp + lk * 8);
    f32x4 d0b = *(const f32x4*)(dwp + lk * 8 + 4);
    f32x4 d1a = *(const f32x4*)(dwp + 32 + lk * 8);
    f32x4 d1b = *(const f32x4*)(dwp + 32 + lk * 8 + 4);
    int rec = (wid + dy + 2) * 20 + (lm + dx + 2);
    h8 v0 = *(const h8*)(smem + rec * RSTR + (lk    ) * 16);
    h8 v1 = *(const h8*)(smem + rec * RSTR + (lk + 4) * 16);
    if (BORDER) {
      int xc2 = tx0 + lm + dx;
      int ry = row + dy;
      bool ok = (xc2 >= 0) & (xc2 < WW) & (ry >= 0) & (ry < HH);
      if (!ok) { v0 = (h8)(_Float16)0.f; v1 = (h8)(_Float16)0.f; }
    }
    #pragma unroll
    for (int e = 0; e < 4; ++e) {
      s[e]      += d0a[e] * (float)v0[e];
      s[4 + e]  += d0b[e] * (float)v0[4 + e];
      s[8 + e]  += d1a[e] * (float)v1[e];
      s[12 + e] += d1b[e] * (float)v1[4 + e];
    }
  }

  // BN + SiLU (rcp form) + pack to f16 B-frags
  h8 bo[2];   // [kc]
  {
    f32x4 ba0 = *(const f32x4*)(bnA + lk * 8);
    f32x4 ba1 = *(const f32x4*)(bnA + lk * 8 + 4);
    f32x4 ba2 = *(const f32x4*)(bnA + 32 + lk * 8);
    f32x4 ba3 = *(const f32x4*)(bnA + 32 + lk * 8 + 4);
    f32x4 bb0 = *(const f32x4*)(bnB + lk * 8);
    f32x4 bb1 = *(const f32x4*)(bnB + lk * 8 + 4);
    f32x4 bb2 = *(const f32x4*)(bnB + 32 + lk * 8);
    f32x4 bb3 = *(const f32x4*)(bnB + 32 + lk * 8 + 4);
    #pragma unroll
    for (int e = 0; e < 4; ++e) {
      float v;
      v = s[e]      * ba0[e] + bb0[e];
      s[e]      = v * __builtin_amdgcn_rcpf(1.f + __expf(-v));
      v = s[4 + e]  * ba1[e] + bb1[e];
      s[4 + e]  = v * __builtin_amdgcn_rcpf(1.f + __expf(-v));
      v = s[8 + e]  * ba2[e] + bb2[e];
      s[8 + e]  = v * __builtin_amdgcn_rcpf(1.f + __expf(-v));
      v = s[12 + e] * ba3[e] + bb3[e];
      s[12 + e] = v * __builtin_amdgcn_rcpf(1.f + __expf(-v));
    }
    #pragma unroll
    for (int e = 0; e < 8; ++e) {
      bo[0][e] = (_Float16)s[e];
      bo[1][e] = (_Float16)s[8 + e];
    }
  }

  // offset MFMA: aco[mt], C-in = padded bias
  f32x4 aco[2];
  aco[0] = *(const f32x4*)(pwb + lk * 4);
  aco[1] = *(const f32x4*)(pwb + 16 + lk * 4);
  #pragma unroll
  for (int kc = 0; kc < 2; ++kc) {
    #pragma unroll
    for (int mt = 0; mt < 2; ++mt) {
      h8 A = *(const h8*)(pwa + (mt * 2 + kc) * 512 + ln * 8);
      aco[mt] = __builtin_amdgcn_mfma_f32_16x16x32_f16(A, bo[kc], aco[mt], 0, 0, 0);
    }
  }

  // ---- pack offsets to f16 pairs; ONE shfl per p.
  unsigned pk0, pk1, pk2;
  {
    h2 a, b2, c;
    a[0]  = (_Float16)aco[0][0]; a[1]  = (_Float16)aco[0][1];
    b2[0] = (_Float16)aco[0][2]; b2[1] = (_Float16)aco[0][3];
    c[0]  = (_Float16)aco[1][0]; c[1]  = (_Float16)aco[1][1];
    pk0 = __builtin_bit_cast(unsigned, a);
    pk1 = __builtin_bit_cast(unsigned, b2);
    pk2 = __builtin_bit_cast(unsigned, c);
  }
  unsigned ov[9];
  ov[0] = __shfl(pk0, 0 * 16 + lm);
  ov[1] = __shfl(pk1, 0 * 16 + lm);
  ov[2] = __shfl(pk0, 1 * 16 + lm);
  ov[3] = __shfl(pk1, 1 * 16 + lm);
  ov[4] = __shfl(pk0, 2 * 16 + lm);
  ov[5] = __shfl(pk1, 2 * 16 + lm);
  ov[6] = __shfl(pk0, 3 * 16 + lm);
  ov[7] = __shfl(pk1, 3 * 16 + lm);
  ov[8] = __shfl(pk2, lm);

  // ======== Phase 2: gather + MFMA ========
  f32x4 acc[4];
  #pragma unroll
  for (int mt = 0; mt < 4; ++mt) acc[mt] = (f32x4){0.f, 0.f, 0.f, 0.f};

  const _Float16* wl = wtf2 + ln * 8;   // + (p*8 + mt*2 + kc)*512

  #pragma unroll
  for (int p = 0; p < PP; ++p) {
    h2 hh = __builtin_bit_cast(h2, ov[p]);
    float sy = (float)hh[0] + (float)(row + p / 3 - 1);
    float sx = (float)hh[1] + (float)(tx0 + lm + p % 3 - 1);

    float y0f = floorf(sy), x0f = floorf(sx);
    float wy1 = sy - y0f, wy0 = 1.f - wy1;
    float wx1 = sx - x0f, wx0 = 1.f - wx1;
    int y0 = (int)y0f, x0i = (int)x0f;

    float w00, w01, w10, w11;
    int r00, r01, r10, r11;
    if (BORDER) {
      bool vy0 = (y0 >= 0) & (y0 < HH);
      bool vy1 = (y0 + 1 >= 0) & (y0 + 1 < HH);
      bool vx0 = (x0i >= 0) & (x0i < WW);
      bool vx1 = (x0i + 1 >= 0) & (x0i + 1 < WW);
      w00 = (vy0 && vx0) ? wy0 * wx0 : 0.f;
      w01 = (vy0 && vx1) ? wy0 * wx1 : 0.f;
      w10 = (vy1 && vx0) ? wy1 * wx0 : 0.f;
      w11 = (vy1 && vx1) ? wy1 * wx1 : 0.f;
      int iy0 = min(max(y0 - ty0 + 2, 0), 7);
      int iy1 = min(max(y0 + 1 - ty0 + 2, 0), 7);
      int ix0 = min(max(x0i - tx0 + 2, 0), 19);
      int ix1 = min(max(x0i + 1 - tx0 + 2, 0), 19);
      r00 = iy0 * 20 + ix0; r01 = iy0 * 20 + ix1;
      r10 = iy1 * 20 + ix0; r11 = iy1 * 20 + ix1;
    } else {
      w00 = wy0 * wx0; w01 = wy0 * wx1;
      w10 = wy1 * wx0; w11 = wy1 * wx1;
      int iy0 = y0 - ty0 + 2;
      int ix0 = x0i - tx0 + 2;
      r00 = iy0 * 20 + ix0; r01 = r00 + 1;
      r10 = r00 + 20;       r11 = r00 + 21;
    }

    h8 v00a = *(const h8*)(smem + r00 * RSTR + (lk    ) * 16);
    h8 v00b = *(const h8*)(smem + r00 * RSTR + (lk + 4) * 16);
    h8 v01a = *(const h8*)(smem + r01 * RSTR + (lk    ) * 16);
    h8 v01b = *(const h8*)(smem + r01 * RSTR + (lk + 4) * 16);
    h8 v10a = *(const h8*)(smem + r10 * RSTR + (lk    ) * 16);
    h8 v10b = *(const h8*)(smem + r10 * RSTR + (lk + 4) * 16);
    h8 v11a = *(const h8*)(smem + r11 * RSTR + (lk    ) * 16);
    h8 v11b = *(const h8*)(smem + r11 * RSTR + (lk + 4) * 16);

    h8 w00v = (h8)(_Float16)w00;
    h8 w01v = (h8)(_Float16)w01;
    h8 w10v = (h8)(_Float16)w10;
    h8 w11v = (h8)(_Float16)w11;
    h8 bf0 = v00a * w00v + v01a * w01v + v10a * w10v + v11a * w11v;
    h8 bf1 = v00b * w00v + v01b * w01v + v10b * w10v + v11b * w11v;

    #pragma unroll
    for (int mt = 0; mt < 4; ++mt) {
      h8 a0 = *(const h8*)(wl + (p * 8 + mt * 2) * 512);
      h8 a1 = *(const h8*)(wl + (p * 8 + mt * 2 + 1) * 512);
      acc[mt] = __builtin_amdgcn_mfma_f32_16x16x32_f16(a0, bf0, acc[mt], 0, 0, 0);
      acc[mt] = __builtin_amdgcn_mfma_f32_16x16x32_f16(a1, bf1, acc[mt], 0, 0, 0);
    }
  }

  // ---- epilogue: C/D layout col=lane&15 (pixel), row=(lane>>4)*4+reg (m)
  int pix = (row << 7) + tx0 + lm;
  #pragma unroll
  for (int mt = 0; mt < 4; ++mt) {
    #pragma unroll
    for (int r = 0; r < 4; ++r) {
      int m = mt * 16 + lk * 4 + r;
      out[((size_t)b * OO + m) * HWIMG + pix] = acc[mt][r] + bias[m];
    }
  }
}

// ---------------------------------------------------------------------------
// Kernel 2: FUSED offsets + gather + MFMA, 4x16 tiles, 2048 blocks.
// LDS: 160*144 = 23040 B -> 6 blocks/CU (138 KB), 24 waves/CU.
// ---------------------------------------------------------------------------
__global__ void __launch_bounds__(256, 6)
k_main(const _Float16* __restrict__ xt,
       const float* __restrict__ dwt,
       const float* __restrict__ bnA,
       const float* __restrict__ bnB,
       const _Float16* __restrict__ pwa,
       const float* __restrict__ pwb,
       const _Float16* __restrict__ wtf2,
       const float* __restrict__ bias,
       float* __restrict__ out) {
  __shared__ __attribute__((aligned(16))) char smem[160 * RSTR];
  int bid = blockIdx.x;
  int b = bid & 7, t = bid >> 3;            // XCD k <- batch k; 256 tiles/img
  int ty0 = (t >> 3) * 4, tx0 = (t & 7) * 16;
  int tid = threadIdx.x;
  const _Float16* xb = xt + (((size_t)b) << 14) * 64;

  bool border = (ty0 == 0) || (ty0 == 124) || (tx0 == 0) || (tx0 == 112);
  if (border)
    tile_body<true >(xb, dwt, bnA, bnB, pwa, pwb, wtf2, bias, out, smem, b, ty0, tx0, tid);
  else
    tile_body<false>(xb, dwt, bnA, bnB, pwa, pwb, wtf2, bias, out, smem, b, ty0, tx0, tid);
}

// ---------------------------------------------------------------------------
extern "C" void kernel_launch(void* const* d_in, const int* in_sizes, int n_in,
                              void* d_out, int out_size, void* d_ws, size_t ws_size,
                              hipStream_t stream) {
  const float* x        = (const float*)d_in[0];
  const float* dw_w     = (const float*)d_in[1];
  const float* dw_b     = (const float*)d_in[2];
  const float* bn_gamma = (const float*)d_in[3];
  const float* bn_beta  = (const float*)d_in[4];
  const float* bn_mean  = (const float*)d_in[5];
  const float* bn_var   = (const float*)d_in[6];
  const float* pw_w     = (const float*)d_in[7];
  const float* pw_b     = (const float*)d_in[8];
  const float* weight   = (const float*)d_in[9];
  const float* bias     = (const float*)d_in[10];
  float* out = (float*)d_out;

  char* ws = (char*)d_ws;
  _Float16* wtf2 = (_Float16*)ws;                              // 73728 B
  size_t o1 = (size_t)PP * OO * CC * 2;
  _Float16* xtb = (_Float16*)(ws + o1);                        // 16.8 MB
  size_t o2 = o1 + (size_t)NTOT * CC * 2;
  float* dwt = (float*)(ws + o2);                              // 2304 B
  float* bnA = (float*)(ws + o2 + 2304);                       // 256 B
  float* bnB = (float*)(ws + o2 + 2304 + 256);                 // 256 B
  _Float16* pwa = (_Float16*)(ws + o2 + 2304 + 512);           // 4096 B
  float* pwb = (float*)(ws + o2 + 2304 + 512 + 4096);          // 128 B

  k_prep<<<145, 256, 0, stream>>>(weight, dw_w, dw_b, bn_gamma, bn_beta,
                                  bn_mean, bn_var, pw_w, pw_b,
                                  wtf2, dwt, bnA, bnB, pwa, pwb);
  k_tr<<<NTOT / 64, 256, 0, stream>>>(x, xtb);
  k_main<<<NTOT / 64, 256, 0, stream>>>(xtb, dwt, bnA, bnB, pwa, pwb,
                                        wtf2, bias, out);
}

// Round 20
// 51.918 us; speedup vs baseline: 1.1199x; 1.1199x over previous
//
#include <hip/hip_runtime.h>
#include <math.h>

#define BB 8
#define CC 64
#define OO 64
#define HH 128
#define WW 128
#define PP 9
#define HWIMG 16384           // H*W per batch
#define NTOT  131072          // B*H*W
#define RSTR 144              // padded halo record stride (16B pad, no swizzle)

typedef __attribute__((ext_vector_type(8))) _Float16 h8;
typedef __attribute__((ext_vector_type(2))) _Float16 h2;
typedef __attribute__((ext_vector_type(4))) float f32x4;

// ---------------------------------------------------------------------------
// Kernel 0: prep (verbatim r18).
// ---------------------------------------------------------------------------
__global__ void k_prep(const float* __restrict__ w,
                       const float* __restrict__ dw_w,
                       const float* __restrict__ dw_b,
                       const float* __restrict__ gamma,
                       const float* __restrict__ beta,
                       const float* __restrict__ mean,
                       const float* __restrict__ var,
                       const float* __restrict__ pw_w,
                       const float* __restrict__ pw_b,
                       _Float16* __restrict__ wtf2,
                       float* __restrict__ dwt,
                       float* __restrict__ bnA,
                       float* __restrict__ bnB,
                       _Float16* __restrict__ pwa,
                       float* __restrict__ pwb) {
  int bid = blockIdx.x, t = threadIdx.x;
  if (bid < 144) {
    int i = bid * 256 + t;
    int e  = i & 7;
    int ln = (i >> 3) & 63;
    int kc = (i >> 9) & 1;
    int mt = (i >> 10) & 3;
    int p  = i >> 12;
    int o = mt * 16 + (ln & 15);
    int c = kc * 32 + (ln >> 4) * 8 + e;
    wtf2[i] = (_Float16)w[(o * 64 + c) * 9 + p];
  } else {
    if (t < 64) {
      float A = gamma[t] * rsqrtf(var[t] + 1e-5f);
      bnA[t] = A;
      bnB[t] = (dw_b[t] - mean[t]) * A + beta[t];
    }
    if (t < 32) pwb[t] = (t < 18) ? pw_b[t] : 0.f;
    for (int i = t; i < 576; i += 256) {
      int tap = i % 9, c = i / 9;
      dwt[tap * 64 + c] = dw_w[c * 9 + tap];
    }
    for (int i = t; i < 2048; i += 256) {
      int e  = i & 7;
      int ln = (i >> 3) & 63;
      int kc = (i >> 9) & 1;
      int mt = (i >> 10) & 1;
      int ko = mt * 16 + (ln & 15);
      int c  = kc * 32 + ((ln >> 4) & 3) * 8 + e;
      pwa[i] = (ko < 18) ? (_Float16)pw_w[ko * 64 + c] : (_Float16)0.f;
    }
  }
}

// ---------------------------------------------------------------------------
// Kernel 1: x NCHW f32 -> xt[b][pix][c] f16 (NHWC) (verbatim, known good)
// ---------------------------------------------------------------------------
__global__ void __launch_bounds__(256, 4)
k_tr(const float* __restrict__ x, _Float16* __restrict__ xt) {
  __shared__ _Float16 lt[64][66];
  int bid = blockIdx.x;
  int vbid = (bid & 7) * 256 + (bid >> 3);    // XCD k <- batch k
  int tid = threadIdx.x;
  int wid = tid >> 6, ln = tid & 63;
  int b = vbid >> 8;
  int pix0 = (vbid & 255) * 64;
  const float* xbb = x + (size_t)b * CC * HWIMG;

  #pragma unroll
  for (int i = 0; i < 8; ++i) {
    int c0 = (wid * 8 + i) * 2;
    float v0 = xbb[(size_t)c0 * HWIMG + pix0 + ln];
    float v1 = xbb[(size_t)(c0 + 1) * HWIMG + pix0 + ln];
    h2 hv;
    hv[0] = (_Float16)v0;
    hv[1] = (_Float16)v1;
    *(h2*)&lt[ln][c0] = hv;
  }
  __syncthreads();

  int pq = tid >> 2, q = tid & 3;
  h8 o0, o1;
  #pragma unroll
  for (int j = 0; j < 4; ++j) {
    h2 v = *(h2*)&lt[pq][q * 16 + 2 * j];
    o0[2 * j] = v[0];
    o0[2 * j + 1] = v[1];
  }
  #pragma unroll
  for (int j = 0; j < 4; ++j) {
    h2 v = *(h2*)&lt[pq][q * 16 + 8 + 2 * j];
    o1[2 * j] = v[0];
    o1[2 * j + 1] = v[1];
  }
  _Float16* op = xt + ((size_t)((b << 14) + pix0 + pq)) * 64 + q * 16;
  *(h8*)op = o0;
  *(h8*)(op + 8) = o1;
}

// ---------------------------------------------------------------------------
// Fused tile body (r18 champion: 8x16 px tile, 12x20 halo @ stride 144,
// de-swizzled LDS, offsets via MFMA, one-shfl offset distribution).
// ---------------------------------------------------------------------------
template<bool BORDER>
__device__ __forceinline__ void tile_body(
    const _Float16* __restrict__ xb,
    const float* __restrict__ dwt,
    const float* __restrict__ bnA,
    const float* __restrict__ bnB,
    const _Float16* __restrict__ pwa,
    const float* __restrict__ pwb,
    const _Float16* __restrict__ wtf2,
    const float* __restrict__ bias,
    float* __restrict__ out,
    char* smem, int b, int ty0, int tx0, int tid) {
  int wid = tid >> 6, ln = tid & 63;
  int lm = ln & 15, lk = ln >> 4;

  // ---- stage 12x20 halo records (row/col-clamped), chunk j -> slot j
  for (int ch = tid; ch < 1920; ch += 256) {
    int rec = ch >> 3, j = ch & 7;
    int ry = rec / 20, rx = rec - ry * 20;
    int yy = min(max(ty0 - 2 + ry, 0), HH - 1);
    int xx = min(max(tx0 - 2 + rx, 0), WW - 1);
    h8 v = *((const h8*)(xb + ((size_t)((yy << 7) + xx)) * 64) + j);
    *(h8*)(smem + rec * RSTR + j * 16) = v;
  }
  __syncthreads();

  int qy0 = wid * 2;
  int y0r = ty0 + qy0;

  // ======== Phase 1: offsets via MFMA ========
  float s[2][16];
  #pragma unroll
  for (int nt = 0; nt < 2; ++nt)
    #pragma unroll
    for (int e = 0; e < 16; ++e) s[nt][e] = 0.f;

  #pragma unroll
  for (int tap = 0; tap < 9; ++tap) {
    int dy = tap / 3 - 1, dx = tap % 3 - 1;
    int xc2 = tx0 + lm + dx;
    bool cok = (xc2 >= 0) & (xc2 < WW);
    const float* dwp = dwt + tap * 64;
    f32x4 d0a = *(const f32x4*)(dwp + lk * 8);
    f32x4 d0b = *(const f32x4*)(dwp + lk * 8 + 4);
    f32x4 d1a = *(const f32x4*)(dwp + 32 + lk * 8);
    f32x4 d1b = *(const f32x4*)(dwp + 32 + lk * 8 + 4);
    #pragma unroll
    for (int nt = 0; nt < 2; ++nt) {
      int rec = (qy0 + nt + dy + 2) * 20 + (lm + dx + 2);
      h8 v0 = *(const h8*)(smem + rec * RSTR + (lk    ) * 16);
      h8 v1 = *(const h8*)(smem + rec * RSTR + (lk + 4) * 16);
      if (BORDER) {
        int ry = y0r + nt + dy;
        bool ok = cok & (ry >= 0) & (ry < HH);
        if (!ok) { v0 = (h8)(_Float16)0.f; v1 = (h8)(_Float16)0.f; }
      }
      #pragma unroll
      for (int e = 0; e < 4; ++e) {
        s[nt][e]      += d0a[e] * (float)v0[e];
        s[nt][4 + e]  += d0b[e] * (float)v0[4 + e];
        s[nt][8 + e]  += d1a[e] * (float)v1[e];
        s[nt][12 + e] += d1b[e] * (float)v1[4 + e];
      }
    }
  }

  // BN + SiLU (rcp form) + pack to f16 B-frags
  h8 bo[2][2];   // [nt][kc]
  {
    f32x4 ba0 = *(const f32x4*)(bnA + lk * 8);
    f32x4 ba1 = *(const f32x4*)(bnA + lk * 8 + 4);
    f32x4 ba2 = *(const f32x4*)(bnA + 32 + lk * 8);
    f32x4 ba3 = *(const f32x4*)(bnA + 32 + lk * 8 + 4);
    f32x4 bb0 = *(const f32x4*)(bnB + lk * 8);
    f32x4 bb1 = *(const f32x4*)(bnB + lk * 8 + 4);
    f32x4 bb2 = *(const f32x4*)(bnB + 32 + lk * 8);
    f32x4 bb3 = *(const f32x4*)(bnB + 32 + lk * 8 + 4);
    #pragma unroll
    for (int nt = 0; nt < 2; ++nt) {
      #pragma unroll
      for (int e = 0; e < 4; ++e) {
        float v;
        v = s[nt][e]      * ba0[e] + bb0[e];
        s[nt][e]      = v * __builtin_amdgcn_rcpf(1.f + __expf(-v));
        v = s[nt][4 + e]  * ba1[e] + bb1[e];
        s[nt][4 + e]  = v * __builtin_amdgcn_rcpf(1.f + __expf(-v));
        v = s[nt][8 + e]  * ba2[e] + bb2[e];
        s[nt][8 + e]  = v * __builtin_amdgcn_rcpf(1.f + __expf(-v));
        v = s[nt][12 + e] * ba3[e] + bb3[e];
        s[nt][12 + e] = v * __builtin_amdgcn_rcpf(1.f + __expf(-v));
      }
      #pragma unroll
      for (int e = 0; e < 8; ++e) {
        bo[nt][0][e] = (_Float16)s[nt][e];
        bo[nt][1][e] = (_Float16)s[nt][8 + e];
      }
    }
  }

  // offset MFMA: aco[mt][nt], C-in = padded bias
  f32x4 aco[2][2];
  {
    f32x4 c0 = *(const f32x4*)(pwb + lk * 4);
    f32x4 c1 = *(const f32x4*)(pwb + 16 + lk * 4);
    aco[0][0] = c0; aco[0][1] = c0;
    aco[1][0] = c1; aco[1][1] = c1;
  }
  #pragma unroll
  for (int kc = 0; kc < 2; ++kc) {
    #pragma unroll
    for (int mt = 0; mt < 2; ++mt) {
      h8 A = *(const h8*)(pwa + (mt * 2 + kc) * 512 + ln * 8);
      #pragma unroll
      for (int nt = 0; nt < 2; ++nt)
        aco[mt][nt] = __builtin_amdgcn_mfma_f32_16x16x32_f16(A, bo[nt][kc], aco[mt][nt], 0, 0, 0);
    }
  }

  // ---- pack offsets to f16 pairs in registers; ONE shfl per (p,nt).
  unsigned pk0[2], pk1[2], pk2[2];
  #pragma unroll
  for (int nt = 0; nt < 2; ++nt) {
    h2 a, b2, c;
    a[0]  = (_Float16)aco[0][nt][0]; a[1]  = (_Float16)aco[0][nt][1];
    b2[0] = (_Float16)aco[0][nt][2]; b2[1] = (_Float16)aco[0][nt][3];
    c[0]  = (_Float16)aco[1][nt][0]; c[1]  = (_Float16)aco[1][nt][1];
    pk0[nt] = __builtin_bit_cast(unsigned, a);
    pk1[nt] = __builtin_bit_cast(unsigned, b2);
    pk2[nt] = __builtin_bit_cast(unsigned, c);
  }

  unsigned ov[2][9];
  #pragma unroll
  for (int nt = 0; nt < 2; ++nt) {
    ov[nt][0] = __shfl(pk0[nt], 0 * 16 + lm);
    ov[nt][1] = __shfl(pk1[nt], 0 * 16 + lm);
    ov[nt][2] = __shfl(pk0[nt], 1 * 16 + lm);
    ov[nt][3] = __shfl(pk1[nt], 1 * 16 + lm);
    ov[nt][4] = __shfl(pk0[nt], 2 * 16 + lm);
    ov[nt][5] = __shfl(pk1[nt], 2 * 16 + lm);
    ov[nt][6] = __shfl(pk0[nt], 3 * 16 + lm);
    ov[nt][7] = __shfl(pk1[nt], 3 * 16 + lm);
    ov[nt][8] = __shfl(pk2[nt], lm);
  }

  // ======== Phase 2: gather + MFMA ========
  f32x4 acc[4][2];     // [mt][nt]
  #pragma unroll
  for (int mt = 0; mt < 4; ++mt)
    #pragma unroll
    for (int nt = 0; nt < 2; ++nt) acc[mt][nt] = (f32x4){0.f, 0.f, 0.f, 0.f};

  const _Float16* wl = wtf2 + ln * 8;   // + (p*8 + mt*2 + kc)*512

  #pragma unroll
  for (int p = 0; p < PP; ++p) {
    h8 bfr[2][2];
    #pragma unroll
    for (int nt = 0; nt < 2; ++nt) {
      h2 hh = __builtin_bit_cast(h2, ov[nt][p]);
      float sy = (float)hh[0] + (float)(y0r + nt + p / 3 - 1);
      float sx = (float)hh[1] + (float)(tx0 + lm + p % 3 - 1);

      float y0f = floorf(sy), x0f = floorf(sx);
      float wy1 = sy - y0f, wy0 = 1.f - wy1;
      float wx1 = sx - x0f, wx0 = 1.f - wx1;
      int y0 = (int)y0f, x0i = (int)x0f;

      float w00, w01, w10, w11;
      int r00, r01, r10, r11;
      if (BORDER) {
        bool vy0 = (y0 >= 0) & (y0 < HH);
        bool vy1 = (y0 + 1 >= 0) & (y0 + 1 < HH);
        bool vx0 = (x0i >= 0) & (x0i < WW);
        bool vx1 = (x0i + 1 >= 0) & (x0i + 1 < WW);
        w00 = (vy0 && vx0) ? wy0 * wx0 : 0.f;
        w01 = (vy0 && vx1) ? wy0 * wx1 : 0.f;
        w10 = (vy1 && vx0) ? wy1 * wx0 : 0.f;
        w11 = (vy1 && vx1) ? wy1 * wx1 : 0.f;
        int iy0 = min(max(y0 - ty0 + 2, 0), 11);
        int iy1 = min(max(y0 + 1 - ty0 + 2, 0), 11);
        int ix0 = min(max(x0i - tx0 + 2, 0), 19);
        int ix1 = min(max(x0i + 1 - tx0 + 2, 0), 19);
        r00 = iy0 * 20 + ix0; r01 = iy0 * 20 + ix1;
        r10 = iy1 * 20 + ix0; r11 = iy1 * 20 + ix1;
      } else {
        w00 = wy0 * wx0; w01 = wy0 * wx1;
        w10 = wy1 * wx0; w11 = wy1 * wx1;
        int iy0 = y0 - ty0 + 2;
        int ix0 = x0i - tx0 + 2;
        r00 = iy0 * 20 + ix0; r01 = r00 + 1;
        r10 = r00 + 20;       r11 = r00 + 21;
      }

      h8 v00a = *(const h8*)(smem + r00 * RSTR + (lk    ) * 16);
      h8 v00b = *(const h8*)(smem + r00 * RSTR + (lk + 4) * 16);
      h8 v01a = *(const h8*)(smem + r01 * RSTR + (lk    ) * 16);
      h8 v01b = *(const h8*)(smem + r01 * RSTR + (lk + 4) * 16);
      h8 v10a = *(const h8*)(smem + r10 * RSTR + (lk    ) * 16);
      h8 v10b = *(const h8*)(smem + r10 * RSTR + (lk + 4) * 16);
      h8 v11a = *(const h8*)(smem + r11 * RSTR + (lk    ) * 16);
      h8 v11b = *(const h8*)(smem + r11 * RSTR + (lk + 4) * 16);

      h8 w00v = (h8)(_Float16)w00;
      h8 w01v = (h8)(_Float16)w01;
      h8 w10v = (h8)(_Float16)w10;
      h8 w11v = (h8)(_Float16)w11;
      bfr[nt][0] = v00a * w00v + v01a * w01v + v10a * w10v + v11a * w11v;
      bfr[nt][1] = v00b * w00v + v01b * w01v + v10b * w10v + v11b * w11v;
    }

    #pragma unroll
    for (int mt = 0; mt < 4; ++mt) {
      h8 a0 = *(const h8*)(wl + (p * 8 + mt * 2) * 512);
      h8 a1 = *(const h8*)(wl + (p * 8 + mt * 2 + 1) * 512);
      #pragma unroll
      for (int nt = 0; nt < 2; ++nt) {
        acc[mt][nt] = __builtin_amdgcn_mfma_f32_16x16x32_f16(a0, bfr[nt][0], acc[mt][nt], 0, 0, 0);
        acc[mt][nt] = __builtin_amdgcn_mfma_f32_16x16x32_f16(a1, bfr[nt][1], acc[mt][nt], 0, 0, 0);
      }
    }
  }

  // ---- epilogue: C/D layout col=lane&15 (pixel), row=(lane>>4)*4+reg (m)
  #pragma unroll
  for (int nt = 0; nt < 2; ++nt) {
    int pix = ((y0r + nt) << 7) + tx0 + lm;
    #pragma unroll
    for (int mt = 0; mt < 4; ++mt) {
      #pragma unroll
      for (int r = 0; r < 4; ++r) {
        int m = mt * 16 + lk * 4 + r;
        out[((size_t)b * OO + m) * HWIMG + pix] = acc[mt][nt][r] + bias[m];
      }
    }
  }
}

// ---------------------------------------------------------------------------
// Kernel 2: FUSED offsets (MFMA) + gather + MFMA, border/interior dispatch.
// LDS: 240 * 144 = 34560 B -> 4 blocks/CU (138 KB < 160 KB).
// ---------------------------------------------------------------------------
__global__ void __launch_bounds__(256, 4)
k_main(const _Float16* __restrict__ xt,
       const float* __restrict__ dwt,
       const float* __restrict__ bnA,
       const float* __restrict__ bnB,
       const _Float16* __restrict__ pwa,
       const float* __restrict__ pwb,
       const _Float16* __restrict__ wtf2,
       const float* __restrict__ bias,
       float* __restrict__ out) {
  __shared__ __attribute__((aligned(16))) char smem[240 * RSTR];
  int bid = blockIdx.x;
  int b = bid & 7, t = bid >> 3;            // XCD k <- batch k; 128 tiles/img
  int ty0 = (t >> 3) * 8, tx0 = (t & 7) * 16;
  int tid = threadIdx.x;
  const _Float16* xb = xt + (((size_t)b) << 14) * 64;

  bool border = (ty0 == 0) || (ty0 == 120) || (tx0 == 0) || (tx0 == 112);
  if (border)
    tile_body<true >(xb, dwt, bnA, bnB, pwa, pwb, wtf2, bias, out, smem, b, ty0, tx0, tid);
  else
    tile_body<false>(xb, dwt, bnA, bnB, pwa, pwb, wtf2, bias, out, smem, b, ty0, tx0, tid);
}

// ---------------------------------------------------------------------------
extern "C" void kernel_launch(void* const* d_in, const int* in_sizes, int n_in,
                              void* d_out, int out_size, void* d_ws, size_t ws_size,
                              hipStream_t stream) {
  const float* x        = (const float*)d_in[0];
  const float* dw_w     = (const float*)d_in[1];
  const float* dw_b     = (const float*)d_in[2];
  const float* bn_gamma = (const float*)d_in[3];
  const float* bn_beta  = (const float*)d_in[4];
  const float* bn_mean  = (const float*)d_in[5];
  const float* bn_var   = (const float*)d_in[6];
  const float* pw_w     = (const float*)d_in[7];
  const float* pw_b     = (const float*)d_in[8];
  const float* weight   = (const float*)d_in[9];
  const float* bias     = (const float*)d_in[10];
  float* out = (float*)d_out;

  char* ws = (char*)d_ws;
  _Float16* wtf2 = (_Float16*)ws;                              // 73728 B
  size_t o1 = (size_t)PP * OO * CC * 2;
  _Float16* xtb = (_Float16*)(ws + o1);                        // 16.8 MB
  size_t o2 = o1 + (size_t)NTOT * CC * 2;
  float* dwt = (float*)(ws + o2);                              // 2304 B
  float* bnA = (float*)(ws + o2 + 2304);                       // 256 B
  float* bnB = (float*)(ws + o2 + 2304 + 256);                 // 256 B
  _Float16* pwa = (_Float16*)(ws + o2 + 2304 + 512);           // 4096 B
  float* pwb = (float*)(ws + o2 + 2304 + 512 + 4096);          // 128 B

  k_prep<<<145, 256, 0, stream>>>(weight, dw_w, dw_b, bn_gamma, bn_beta,
                                  bn_mean, bn_var, pw_w, pw_b,
                                  wtf2, dwt, bnA, bnB, pwa, pwb);
  k_tr<<<NTOT / 64, 256, 0, stream>>>(x, xtb);
  k_main<<<NTOT / 128, 256, 0, stream>>>(xtb, dwt, bnA, bnB, pwa, pwb,
                                         wtf2, bias, out);
}